// Round 19
// baseline (4853.481 us; speedup 1.0000x reference)
//
#include <hip/hip_runtime.h>
#include <cstddef>

// WordEncoder: emb gather -> masked LSTM (T=1024) -> relu(h@Wd+bd)
// R19 = R18 + gate-major in-register gates:
//  - weight cols remapped to col = gate*256 + u0 + cq, so after the DPP
//    rowsum each 16-lane row holds the full 4-gate z of (batch r, unit
//    u0+cq). Lanes ksl<4 compute gates in-register and publish -- from ALL
//    4 waves in parallel. zs LDS round-trip, barrier B, and the wave-0
//    gate serialization are deleted (publish ~700-900cy earlier).
//  - protocol reverts to pure R8: bare dual-publish (workgroup->L2 +
//    agent->IC), tag-validated, bounded L2 re-poll with sticky IC
//    fallback. No certificate, no init kernel, no drains (R12's poison).
// Kept from R18: 512 blocks = 16bg x 32ug 2/CU, pk_fma GEMM, int4-batched
// tokens, late packet sample. Tags validate every value (placement-
// independent); tag=step+1 makes zero-init/replay-stale packets benign.

typedef unsigned int u32x4 __attribute__((ext_vector_type(4)));
typedef float f32x2 __attribute__((ext_vector_type(2)));
typedef float f32x4 __attribute__((ext_vector_type(4)));

constexpr int TLEN = 1024;
constexpr int EDIM = 128;
constexpr int UDIM = 256;
constexpr int DDIM = 256;

constexpr int BPB  = 8;    // batches per block
constexpr int UPB  = 8;    // units per block
constexpr int HXROW = 432; // (384/32)*36 padded row

__device__ unsigned long long g_pktA[2][128][256]; // XCD-local path (L2)
__device__ unsigned long long g_pktB[2][128][256]; // device-coherent mirror (IC)

__device__ __forceinline__ int pidx(int k) { return ((k >> 5) * 36) + (k & 31); }

__device__ __forceinline__ u32x4 pkt_load_ic(const unsigned long long* p) {
  u32x4 v;
  asm volatile("global_load_dwordx4 %0, %1, off sc0 sc1" : "=v"(v) : "v"(p));
  return v;
}
__device__ __forceinline__ u32x4 pkt_load_l2(const unsigned long long* p) {
  u32x4 v; // sc0: bypass L1, hit the XCD-coherent L2
  asm volatile("global_load_dwordx4 %0, %1, off sc0" : "=v"(v) : "v"(p));
  return v;
}
#define PKT_WAIT4(a, b, c, d) \
  asm volatile("s_waitcnt vmcnt(0)" : "+v"(a), "+v"(b), "+v"(c), "+v"(d) :: "memory")
#define TAGS_OK() \
  ((p0[1] == want) & (p0[3] == want) & (p1[1] == want) & (p1[3] == want) & \
   (p2[1] == want) & (p2[3] == want) & (p3[1] == want) & (p3[3] == want))

// Packed dual-FMA: acc(pair) += broadcast(h2.lo or h2.hi) * w(pair).
#define PK_FMA_LO(acc, h2, wp)                                              \
  asm("v_pk_fma_f32 %0, %1, %2, %0 op_sel:[0,0,0] op_sel_hi:[0,1,1]"        \
      : "+v"(acc) : "v"(h2), "v"(wp))
#define PK_FMA_HI(acc, h2, wp)                                              \
  asm("v_pk_fma_f32 %0, %1, %2, %0 op_sel:[1,0,0] op_sel_hi:[1,1,1]"        \
      : "+v"(acc) : "v"(h2), "v"(wp))

// Sum across the 16-lane DPP row (ksl groups == DPP rows). Pure VALU pipe.
__device__ __forceinline__ float rowsum16(float v) {
  v += __int_as_float(
      __builtin_amdgcn_mov_dpp(__float_as_int(v), 0x121, 0xf, 0xf, true));
  v += __int_as_float(
      __builtin_amdgcn_mov_dpp(__float_as_int(v), 0x122, 0xf, 0xf, true));
  v += __int_as_float(
      __builtin_amdgcn_mov_dpp(__float_as_int(v), 0x124, 0xf, 0xf, true));
  v += __int_as_float(
      __builtin_amdgcn_mov_dpp(__float_as_int(v), 0x128, 0xf, 0xf, true));
  return v;
}

__global__ __launch_bounds__(256, 2) void we_lstm(
    const int* __restrict__ tokens, const float* __restrict__ emb,
    const float* __restrict__ Wk, const float* __restrict__ Wr,
    const float* __restrict__ bz, float* __restrict__ out)
{
  __shared__ float hx[2][BPB][HXROW]; // parity-dbuf [h(256)|x(128)], padded

  const int tid = threadIdx.x;
  const int bid = blockIdx.x;
  // Group remap: a bg's 32 blocks share bid%8 (one XCD under round-robin);
  // co-resident pair (bid, bid+256) -> same CU, different bg.
  const int bg  = ((bid & 7) << 1) | ((bid >> 8) & 1);
  const int ug  = (bid >> 3) & 31;
  const int b0  = bg * BPB;
  const int u0  = ug * UPB;

  // GEMM decomposition: 256 = 2 row-halves x 8 col-quads x 16 k-slices;
  // 4 batch rows/thread. k = ksl*4 + i*64 + j ; i<4 h-part, i>=4 x-part.
  // GATE-MAJOR cols: lane's 4 cols = gates {i,f,g,o} of unit u0+cq.
  const int ksl = tid & 15;
  const int cq  = (tid >> 4) & 7;
  const int bh  = tid >> 7;

  // ---- prologue: weight slice as f32x2 pairs (24k x 4c per thread) ----
  f32x2 w2[48]; // [(i*4+j)*2 + p] = gates {2p, 2p+1} of unit u0+cq at k
#pragma unroll
  for (int i = 0; i < 6; ++i)
#pragma unroll
    for (int j = 0; j < 4; ++j) {
      const int k = ksl * 4 + i * 64 + j;
#pragma unroll
      for (int p = 0; p < 2; ++p) {
        f32x2 wp;
#pragma unroll
        for (int e = 0; e < 2; ++e) {
          const int col = ((p * 2 + e) << 8) + u0 + cq;
          wp[e] = (k < UDIM) ? Wr[k * 1024 + col] : Wk[(k - UDIM) * 1024 + col];
        }
        w2[(i * 4 + j) * 2 + p] = wp;
      }
    }
  float bias_r[4];
#pragma unroll
  for (int cc = 0; cc < 4; ++cc) bias_r[cc] = bz[(cc << 8) + u0 + cq];

  float creg = 0.f;
  const int bat = bh * 4 + (ksl & 3);            // gate lane's batch (ksl<4)
  const int xb = tid >> 5, xe = (tid & 31) << 2; // x stage
  const int up = tid & 127, bq = (tid >> 7) * 4; // pkt stage

  bool use_local = true; // self-tuning exchange path (sticky downgrade)

  const int row_x = (b0 + xb) * TLEN;
  const int row_m = (b0 + bat) * TLEN;

  // ---- token quads for steps 0..3 + x(0) prefetch ----
  int4 tcx = *(const int4*)&tokens[row_x];
  int4 tcm = *(const int4*)&tokens[row_m];
  float4 xv = *(const float4*)&emb[(size_t)tcx.x * EDIM + xe];

  u32x4 p0, p1, p2, p3;

  // One LSTM step; cur is compile-time at each call site.
  auto step = [&](const int it, const int cur, const int tok_next,
                  const int tkm) {
    // ---- write prefetched x -> LDS ----
    *(float4*)&hx[cur][xb][pidx(UDIM + xe)] = xv;
    __syncthreads(); // X: x staged

    f32x2 acc2[4][2];
#pragma unroll
    for (int r = 0; r < 4; ++r) {
      acc2[r][0] = (f32x2)(0.f);
      acc2[r][1] = (f32x2)(0.f);
    }
    // ---- x-part GEMM (i=4,5), packed dual-FMA ----
#pragma unroll
    for (int i = 4; i < 6; ++i) {
      const int hoff = pidx(ksl * 4 + i * 64);
#pragma unroll
      for (int r = 0; r < 4; ++r) {
        const f32x4 hv = *(const f32x4*)&hx[cur][bh * 4 + r][hoff];
        const f32x2 hlo = __builtin_shufflevector(hv, hv, 0, 1);
        const f32x2 hhi = __builtin_shufflevector(hv, hv, 2, 3);
        PK_FMA_LO(acc2[r][0], hlo, w2[(i * 4 + 0) * 2 + 0]);
        PK_FMA_LO(acc2[r][1], hlo, w2[(i * 4 + 0) * 2 + 1]);
        PK_FMA_HI(acc2[r][0], hlo, w2[(i * 4 + 1) * 2 + 0]);
        PK_FMA_HI(acc2[r][1], hlo, w2[(i * 4 + 1) * 2 + 1]);
        PK_FMA_LO(acc2[r][0], hhi, w2[(i * 4 + 2) * 2 + 0]);
        PK_FMA_LO(acc2[r][1], hhi, w2[(i * 4 + 2) * 2 + 1]);
        PK_FMA_HI(acc2[r][0], hhi, w2[(i * 4 + 3) * 2 + 0]);
        PK_FMA_HI(acc2[r][1], hhi, w2[(i * 4 + 3) * 2 + 1]);
      }
    }

    // ---- emb gather for x(it+1): register token, no dependent wait ----
    float4 xv_n;
    if (it + 1 < TLEN)
      xv_n = *(const float4*)&emb[(size_t)tok_next * EDIM + xe];

    // ---- LATE packet sample + resolve (tags -> bounded L2 -> sticky IC) --
    const unsigned want = (unsigned)it; // producer tag = step+1
    const int rp = cur ^ 1;             // == (it-1)&1
    const int ho = pidx(2 * up);
    if (it > 0) {
      if (use_local) {
        p0 = pkt_load_l2(&g_pktA[rp][b0 + bq + 0][2 * up]);
        p1 = pkt_load_l2(&g_pktA[rp][b0 + bq + 1][2 * up]);
        p2 = pkt_load_l2(&g_pktA[rp][b0 + bq + 2][2 * up]);
        p3 = pkt_load_l2(&g_pktA[rp][b0 + bq + 3][2 * up]);
      } else {
        p0 = pkt_load_ic(&g_pktB[rp][b0 + bq + 0][2 * up]);
        p1 = pkt_load_ic(&g_pktB[rp][b0 + bq + 1][2 * up]);
        p2 = pkt_load_ic(&g_pktB[rp][b0 + bq + 2][2 * up]);
        p3 = pkt_load_ic(&g_pktB[rp][b0 + bq + 3][2 * up]);
      }
      PKT_WAIT4(p0, p1, p2, p3);
      bool ok = TAGS_OK();
      if (!ok && use_local) {
        int rounds = 0;
        do {
          __builtin_amdgcn_s_sleep(1);
          p0 = pkt_load_l2(&g_pktA[rp][b0 + bq + 0][2 * up]);
          p1 = pkt_load_l2(&g_pktA[rp][b0 + bq + 1][2 * up]);
          p2 = pkt_load_l2(&g_pktA[rp][b0 + bq + 2][2 * up]);
          p3 = pkt_load_l2(&g_pktA[rp][b0 + bq + 3][2 * up]);
          PKT_WAIT4(p0, p1, p2, p3);
          ok = TAGS_OK();
        } while (!ok && ++rounds < 128);
        if (!ok) use_local = false; // cross-XCD placement: downgrade for good
      }
      while (!ok) {
        p0 = pkt_load_ic(&g_pktB[rp][b0 + bq + 0][2 * up]);
        p1 = pkt_load_ic(&g_pktB[rp][b0 + bq + 1][2 * up]);
        p2 = pkt_load_ic(&g_pktB[rp][b0 + bq + 2][2 * up]);
        p3 = pkt_load_ic(&g_pktB[rp][b0 + bq + 3][2 * up]);
        PKT_WAIT4(p0, p1, p2, p3);
        ok = TAGS_OK();
        if (!ok) __builtin_amdgcn_s_sleep(1);
      }
      *(float2*)&hx[cur][bq + 0][ho] =
          make_float2(__uint_as_float(p0[0]), __uint_as_float(p0[2]));
      *(float2*)&hx[cur][bq + 1][ho] =
          make_float2(__uint_as_float(p1[0]), __uint_as_float(p1[2]));
      *(float2*)&hx[cur][bq + 2][ho] =
          make_float2(__uint_as_float(p2[0]), __uint_as_float(p2[2]));
      *(float2*)&hx[cur][bq + 3][ho] =
          make_float2(__uint_as_float(p3[0]), __uint_as_float(p3[2]));
    } else {
#pragma unroll
      for (int jj = 0; jj < 4; ++jj)
        *(float2*)&hx[cur][bq + jj][ho] = make_float2(0.f, 0.f);
    }
    __syncthreads(); // A: h staged

    // ---- h-part GEMM (i=0..3), packed dual-FMA ----
#pragma unroll
    for (int i = 0; i < 4; ++i) {
      const int hoff = pidx(ksl * 4 + i * 64);
#pragma unroll
      for (int r = 0; r < 4; ++r) {
        const f32x4 hv = *(const f32x4*)&hx[cur][bh * 4 + r][hoff];
        const f32x2 hlo = __builtin_shufflevector(hv, hv, 0, 1);
        const f32x2 hhi = __builtin_shufflevector(hv, hv, 2, 3);
        PK_FMA_LO(acc2[r][0], hlo, w2[(i * 4 + 0) * 2 + 0]);
        PK_FMA_LO(acc2[r][1], hlo, w2[(i * 4 + 0) * 2 + 1]);
        PK_FMA_HI(acc2[r][0], hlo, w2[(i * 4 + 1) * 2 + 0]);
        PK_FMA_HI(acc2[r][1], hlo, w2[(i * 4 + 1) * 2 + 1]);
        PK_FMA_LO(acc2[r][0], hhi, w2[(i * 4 + 2) * 2 + 0]);
        PK_FMA_LO(acc2[r][1], hhi, w2[(i * 4 + 2) * 2 + 1]);
        PK_FMA_HI(acc2[r][0], hhi, w2[(i * 4 + 3) * 2 + 0]);
        PK_FMA_HI(acc2[r][1], hhi, w2[(i * 4 + 3) * 2 + 1]);
      }
    }

    // hazard guard: inline-asm pk_fma defs feed DPP reads below.
    asm volatile("s_nop 1");

    // ---- k-reduce via DPP row_ror; every row-lane gets (batch r)'s full z -
    float zsum[4][4]; // [r][gate] -- all indices static
#pragma unroll
    for (int r = 0; r < 4; ++r) {
      zsum[r][0] = rowsum16(acc2[r][0].x);
      zsum[r][1] = rowsum16(acc2[r][0].y);
      zsum[r][2] = rowsum16(acc2[r][1].x);
      zsum[r][3] = rowsum16(acc2[r][1].y);
    }

    // ---- in-register gates + publish: lanes ksl<4, ALL 4 waves ----
    if (ksl < 4) {
      float z0, z1, z2, z3;
      if (ksl == 0)      { z0 = zsum[0][0]; z1 = zsum[0][1]; z2 = zsum[0][2]; z3 = zsum[0][3]; }
      else if (ksl == 1) { z0 = zsum[1][0]; z1 = zsum[1][1]; z2 = zsum[1][2]; z3 = zsum[1][3]; }
      else if (ksl == 2) { z0 = zsum[2][0]; z1 = zsum[2][1]; z2 = zsum[2][2]; z3 = zsum[2][3]; }
      else               { z0 = zsum[3][0]; z1 = zsum[3][1]; z2 = zsum[3][2]; z3 = zsum[3][3]; }
      const float zi = z0 + bias_r[0];
      const float zf = z1 + bias_r[1];
      const float zg = z2 + bias_r[2];
      const float zo = z3 + bias_r[3];
      const float gi = 1.f / (1.f + __expf(-zi));
      const float gf = 1.f / (1.f + __expf(-zf));
      const float gg = 1.f - 2.f / (1.f + __expf(2.f * zg)); // tanh
      const float go = 1.f / (1.f + __expf(-zo));
      const float cn = gf * creg + gi * gg;
      const float th = 1.f - 2.f / (1.f + __expf(2.f * cn));
      const float hn = go * th;
      const bool msk = (tkm != 0);
      const float hold = hx[cur][bat][pidx(u0 + cq)];
      const float h2 = msk ? hn : hold;
      creg = msk ? cn : creg;
      const unsigned long long pkt =
          ((unsigned long long)(unsigned)(it + 1) << 32) | __float_as_uint(h2);
      __hip_atomic_store(&g_pktA[cur][b0 + bat][u0 + cq], pkt, __ATOMIC_RELAXED,
                         __HIP_MEMORY_SCOPE_WORKGROUP);
      __hip_atomic_store(&g_pktB[cur][b0 + bat][u0 + cq], pkt, __ATOMIC_RELAXED,
                         __HIP_MEMORY_SCOPE_AGENT);
      __builtin_nontemporal_store(
          h2, &out[((size_t)(b0 + bat) * TLEN + it) * DDIM + u0 + cq]);
    }
    xv = xv_n;
    // no barrier here: next step writes only hx[1-cur] before barrier X,
    // while gates read hx[cur] -- disjoint; barrier X orders the rest.
  };

  for (int itb = 0; itb < TLEN; itb += 4) {
    // refill next token quads (dependency-free; age under this quad's GEMMs)
    const int nb = (itb + 4 < TLEN) ? itb + 4 : itb;
    const int4 tnx = *(const int4*)&tokens[row_x + nb];
    const int4 tnm = *(const int4*)&tokens[row_m + nb];
    step(itb + 0, 0, tcx.y, tcm.x);
    step(itb + 1, 1, tcx.z, tcm.y);
    step(itb + 2, 0, tcx.w, tcm.z);
    step(itb + 3, 1, tnx.x, tcm.w);
    tcx = tnx;
    tcm = tnm;
  }
}

// y = relu(H @ Wd + bd), in place over d_out (h history -> y). 32 rows/block.
__global__ __launch_bounds__(256, 2) void we_proj(
    const float* __restrict__ Wd, const float* __restrict__ bd,
    float* __restrict__ out)
{
  __shared__ float hs[32][260];
  __shared__ float ws[32][260];
  __shared__ float bds[DDIM];

  const int tid = threadIdx.x;
  const size_t row0 = (size_t)blockIdx.x * 32;

#pragma unroll
  for (int j2 = 0; j2 < 8; ++j2) {
    const int idx = tid + j2 * 256;
    const int r = idx >> 6;
    const int cq = idx & 63;
    *(float4*)&hs[r][cq * 4] = *(const float4*)&out[(row0 + r) * DDIM + cq * 4];
  }
  bds[tid] = bd[tid];

  const int rg = tid >> 5;
  const int c0 = (tid & 31) * 8;
  float acc[4][8];
#pragma unroll
  for (int i = 0; i < 4; ++i)
#pragma unroll
    for (int c = 0; c < 8; ++c) acc[i][c] = 0.f;

  for (int kt = 0; kt < 8; ++kt) {
    __syncthreads();
#pragma unroll
    for (int j2 = 0; j2 < 8; ++j2) {
      const int idx = tid + j2 * 256;
      const int kk = idx >> 6;
      const int cq = idx & 63;
      *(float4*)&ws[kk][cq * 4] =
          *(const float4*)&Wd[(size_t)(kt * 32 + kk) * DDIM + cq * 4];
    }
    __syncthreads();
#pragma unroll
    for (int kk = 0; kk < 32; ++kk) {
      const float4 wv0 = *(const float4*)&ws[kk][c0];
      const float4 wv1 = *(const float4*)&ws[kk][c0 + 4];
#pragma unroll
      for (int i = 0; i < 4; ++i) {
        const float hval = hs[rg + i * 8][kt * 32 + kk];
        acc[i][0] += hval * wv0.x; acc[i][1] += hval * wv0.y;
        acc[i][2] += hval * wv0.z; acc[i][3] += hval * wv0.w;
        acc[i][4] += hval * wv1.x; acc[i][5] += hval * wv1.y;
        acc[i][6] += hval * wv1.z; acc[i][7] += hval * wv1.w;
      }
    }
  }
#pragma unroll
  for (int i = 0; i < 4; ++i) {
    float4 y0, y1;
    y0.x = fmaxf(acc[i][0] + bds[c0 + 0], 0.f);
    y0.y = fmaxf(acc[i][1] + bds[c0 + 1], 0.f);
    y0.z = fmaxf(acc[i][2] + bds[c0 + 2], 0.f);
    y0.w = fmaxf(acc[i][3] + bds[c0 + 3], 0.f);
    y1.x = fmaxf(acc[i][4] + bds[c0 + 4], 0.f);
    y1.y = fmaxf(acc[i][5] + bds[c0 + 5], 0.f);
    y1.z = fmaxf(acc[i][6] + bds[c0 + 6], 0.f);
    y1.w = fmaxf(acc[i][7] + bds[c0 + 7], 0.f);
    const size_t orow = (row0 + rg + i * 8) * DDIM;
    *(float4*)&out[orow + c0]     = y0;
    *(float4*)&out[orow + c0 + 4] = y1;
  }
}

extern "C" void kernel_launch(void* const* d_in, const int* in_sizes, int n_in,
                              void* d_out, int out_size, void* d_ws, size_t ws_size,
                              hipStream_t stream) {
  const int*   tokens = (const int*)d_in[0];
  const float* emb    = (const float*)d_in[1];
  const float* Wk     = (const float*)d_in[2];
  const float* Wr     = (const float*)d_in[3];
  const float* bz     = (const float*)d_in[4];
  const float* Wd     = (const float*)d_in[5];
  const float* bd     = (const float*)d_in[6];
  float* out = (float*)d_out;
  (void)in_sizes; (void)n_in; (void)out_size; (void)d_ws; (void)ws_size;
  hipLaunchKernelGGL(we_lstm, dim3(512), dim3(256), 0, stream,
                     tokens, emb, Wk, Wr, bz, out);
  hipLaunchKernelGGL(we_proj, dim3(128 * TLEN / 32), dim3(256), 0, stream,
                     Wd, bd, out);
}